// Round 1
// baseline (188.670 us; speedup 1.0000x reference)
//
#include <hip/hip_runtime.h>
#include <hip/hip_bf16.h>

// Bundle-adjustment reprojection residual:
//   p_cam = R(q) * point + t   (via quaternion: p + 2*qv x (qv x p + qw*p) + t)
//   img   = K * p_cam ;  res = img.xy/img.z - obs
// N_OBS = 5e6, one thread per observation. Memory-bound gather kernel.

#define N_OBS_EXPECTED 5000000

__global__ __launch_bounds__(256) void resid_kernel(
    const float2* __restrict__ obs,    // [N_OBS] (x,y)
    const float*  __restrict__ Kmat,   // [9] row-major
    const float*  __restrict__ poses,  // [N_CAM*7] t(3), qv(3), qw
    const float*  __restrict__ points, // [N_PTS*3]
    const int*    __restrict__ cidx,   // [N_OBS]
    const int*    __restrict__ pidx,   // [N_OBS]
    float2*       __restrict__ out,    // [N_OBS] residual pairs
    int n)
{
    int i = blockIdx.x * blockDim.x + threadIdx.x;
    if (i >= n) return;

    int c = cidx[i];
    int p = pidx[i];

    const float* ps = poses + 7 * c;
    float tx = ps[0], ty = ps[1], tz = ps[2];
    float qx = ps[3], qy = ps[4], qz = ps[5], qw = ps[6];

    const float* pt = points + 3 * p;
    float px = pt[0], py = pt[1], pz = pt[2];

    // uv = qv x p
    float ux = qy * pz - qz * py;
    float uy = qz * px - qx * pz;
    float uz = qx * py - qy * px;
    // w = uv + qw * p
    float wx = ux + qw * px;
    float wy = uy + qw * py;
    float wz = uz + qw * pz;
    // cc = qv x w
    float ccx = qy * wz - qz * wy;
    float ccy = qz * wx - qx * wz;
    float ccz = qx * wy - qy * wx;
    // p_cam = p + 2*cc + t
    float X = px + 2.0f * ccx + tx;
    float Y = py + 2.0f * ccy + ty;
    float Z = pz + 2.0f * ccz + tz;

    // K = [[fx,0,cx],[0,fy,cy],[0,0,1]]
    float fx = Kmat[0], cx = Kmat[2];
    float fy = Kmat[4], cy = Kmat[5];

    float invz = 1.0f / Z;
    float2 o = obs[i];
    float2 r;
    r.x = (fx * X) * invz + cx - o.x;
    r.y = (fy * Y) * invz + cy - o.y;
    out[i] = r;
}

extern "C" void kernel_launch(void* const* d_in, const int* in_sizes, int n_in,
                              void* d_out, int out_size, void* d_ws, size_t ws_size,
                              hipStream_t stream) {
    const float2* obs    = (const float2*)d_in[0];  // observes [N_OBS,2]
    const float*  Kmat   = (const float*)d_in[1];   // K [3,3]
    const float*  poses  = (const float*)d_in[2];   // poses [N_CAM,7]
    const float*  points = (const float*)d_in[3];   // points [N_PTS,3]
    const int*    cidx   = (const int*)d_in[4];     // [N_OBS]
    const int*    pidx   = (const int*)d_in[5];     // [N_OBS]
    float2*       out    = (float2*)d_out;          // [N_OBS,2] flattened

    int n = in_sizes[4];  // N_OBS (element count of cidx)
    int block = 256;
    int grid = (n + block - 1) / block;
    resid_kernel<<<grid, block, 0, stream>>>(obs, Kmat, poses, points, cidx, pidx, out, n);
}